// Round 5
// baseline (1711.179 us; speedup 1.0000x reference)
//
#include <hip/hip_runtime.h>
#include <hip/hip_bf16.h>

// Sizes (fixed by the problem)
#define B_   256
#define E_   256
#define H_   256
#define T_   512
#define OUT_ 702
#define G4H  1024   // 4*H

typedef _Float16 half8 __attribute__((ext_vector_type(8)));
typedef float    floatx4 __attribute__((ext_vector_type(4)));
typedef unsigned long long ull;

// Workspace layout (bytes). Total ~69.6 MB. (R3-verified offsets)
// hbuf: 4 slots x 16 groups x 16 rows x 64 words x 8B = 512 KB.
//   Word = ~(4 packed fp16). 0 == "not yet written". Slot t&3; producer
//   re-zeroes its own word of slot (t-2)&3 alongside publishing t; the
//   step-t gather's trailing vmcnt(0) commits both before publish(t+1)
//   -> consumer that observed publish(t+1) can never see stale slot data.
#define OFF_DTF    0                          // 1 int dtype flag
#define OFF_HBUF   4096                       // 524288 bytes
#define OFF_BASE   (4096 + 524288)            // 256*1024 fp32 = 1 MB
#define OFF_WC16   (OFF_BASE + 1048576)       // 1024*256 fp16 (W_ih + W_hh)
#define OFF_WREC16 (OFF_WC16 + 524288)        // 704*256 fp16 (zero-pad 702..703)
#define OFF_HS16   (OFF_WREC16 + 360448)      // 256*512*256 fp16 = 64 MB

__device__ __forceinline__ float ldin(const void* p, long i, int bf) {
  return bf ? __bfloat162float(((const __hip_bfloat16*)p)[i]) : ((const float*)p)[i];
}
__device__ __forceinline__ void stout(void* p, long i, float v, int bf) {
  if (bf) ((__hip_bfloat16*)p)[i] = __float2bfloat16(v);
  else    ((float*)p)[i] = v;
}
__device__ __forceinline__ float sigf(float x)  { return 1.0f / (1.0f + __expf(-x)); }
__device__ __forceinline__ float tanh_(float x) { float e = __expf(2.0f * x); return 1.0f - 2.0f / (e + 1.0f); }

// ---------------------------------------------------------------------------
// K0: runtime input-dtype detection (unchanged).
__global__ void k_detect(const unsigned int* emb, int* dtf) {
  int tid = threadIdx.x;
  int cnt = 0;
  for (int i = tid; i < 256; i += 64) {
    unsigned int u = emb[i];
    unsigned int e = (u >> 7) & 0xFF;
    cnt += (e >= 100 && e <= 129) ? 1 : 0;
  }
  for (int off = 32; off > 0; off >>= 1) cnt += __shfl_down(cnt, off);
  if (tid == 0) *dtf = (cnt >= 128) ? 1 : 0;
}

// K1: W_comb = W_ih + W_hh -> fp16  [1024][256]
__global__ void k_prep_wc(const void* wih, const void* whh, _Float16* wc, const int* dtf) {
  int bf = *dtf;
  long i = (long)blockIdx.x * 256 + threadIdx.x;
  wc[i] = (_Float16)(ldin(wih, i, bf) + ldin(whh, i, bf));
}

// K1b: W_rec -> fp16, padded to [704][256] with zeros
__global__ void k_prep_wrec(const void* wrec, _Float16* wr, const int* dtf) {
  int bf = *dtf;
  long i = (long)blockIdx.x * 256 + threadIdx.x;   // < 704*256
  wr[i] = (i < (long)OUT_ * H_) ? (_Float16)ldin(wrec, i, bf) : (_Float16)0.0f;
}

// K2: base[b][n] = x0[b]·W_ih[n] + b_ih[n] + b_hh[n]   (fp32, exact)
__global__ void k_prep_base(const void* emb, const void* wih, const void* bih,
                            const void* bhh, float* base, const int* dtf) {
  int bf = *dtf;
  int b = blockIdx.x >> 2;
  int n = (blockIdx.x & 3) * 256 + threadIdx.x;
  __shared__ float x0s[256];
  x0s[threadIdx.x] = ldin(emb, (long)b * E_ + threadIdx.x, bf);
  __syncthreads();
  float acc = ldin(bih, n, bf) + ldin(bhh, n, bf);
  const long wrow = (long)n * E_;
  for (int k = 0; k < E_; ++k) acc += x0s[k] * ldin(wih, wrow + k, bf);
  base[(long)b * G4H + n] = acc;
}

// ---------------------------------------------------------------------------
// K3: persistent LSTM recurrence, GATE-INTERLEAVED MFMA tiles (audited).
// Lane r of a wave = (gate gid = r>>2, local col cl = r&3); B-frag row =
// gid*256 + mycol — the i,f,g,o of one (row,col) land in 4 lanes of the
// SAME wave and are exchanged with 3 rotated shuffles (round cc: sender
// offers acc[(gid+cc)&3]; receiver reads lane (q, ((gid-cc)&3)*4+cl),
// obtaining that lane's acc[gid] == gate (gid-cc)&3 at row q*4+gid).
// gates_lds + its sync are DELETED; h_lds double-buffered -> exactly ONE
// syncthreads per step; publish issues ~300cyc earlier.
// Exchange protocol (slots/sentinel/unique-poll) = R3 verified.
__global__ void __launch_bounds__(256) k_lstm(char* ws, void* dout, const int* dtf) {
  const int bf  = *dtf;
  const int tid = threadIdx.x;
  const int g   = blockIdx.x >> 4;
  const int mem = blockIdx.x & 15;
  const int wid = tid >> 6;
  const int lane = tid & 63;
  const int q = lane >> 4;
  const int r = lane & 15;
  const int gid = r >> 2;     // gate id owned by this lane
  const int cl  = r & 3;      // local col within the wave's 4 hidden cols

  _Float16* wc   = (_Float16*)(ws + OFF_WC16);
  float*    base = (float*)(ws + OFF_BASE);
  ull*      hbuf = (ull*)(ws + OFF_HBUF);
  _Float16* hs16 = (_Float16*)(ws + OFF_HS16);

  const int mycol = mem * 16 + wid * 4 + cl;   // owned hidden col
  const int myrow = q * 4 + gid;               // owned batch row (local)

  // B-fragments: Wc row = gid*256 + mycol (gate-interleaved tile columns)
  half8 wfrag[8];
  {
    const long wrow = (long)(gid * 256 + mycol) * H_;
#pragma unroll
    for (int kb = 0; kb < 8; ++kb)
      wfrag[kb] = *(const half8*)(wc + wrow + kb * 32 + q * 8);
  }
  float basev[4];
  {
    const long brow = (long)(g * 16 + myrow) * G4H + mycol;
#pragma unroll
    for (int G = 0; G < 4; ++G) basev[G] = base[brow + G * 256];
  }

  __shared__ _Float16 h_lds[2][16][264];   // double-buffered; 528B stride: 2-way free
  for (int i = tid; i < 2 * 16 * 264; i += 256) (&h_lds[0][0][0])[i] = (_Float16)0.0f;
  float c = 0.0f;
  __syncthreads();

  const long out2off = (long)B_ * T_ * OUT_;
  const long orow_base = ((long)(g * 16 + myrow) * T_) * H_ + mycol;

  const bool packer = (cl == 0);
  const int pword = (g * 16 + myrow) * 64 + mem * 4 + wid;
  const int grow = g * 16 + wid * 4;   // gather: wave wid polls rows 4wid+i, wordcol=lane

  int cur = 0;
  for (int t = 0; t < T_; ++t) {
    // gates tile: rows = batch, cols = gate-interleaved (4 gates x 4 cols)
    floatx4 acc = {0.f, 0.f, 0.f, 0.f};
#pragma unroll
    for (int kb = 0; kb < 8; ++kb) {
      half8 a = *(const half8*)(&h_lds[cur][r][kb * 32 + q * 8]);
      acc = __builtin_amdgcn_mfma_f32_16x16x32_f16(a, wfrag[kb], acc, 0, 0, 0);
    }
    // rotation exchange: collect all 4 gates at e = gid (3 shuffles, no LDS)
    float a0 = acc[0], a1 = acc[1], a2 = acc[2], a3 = acc[3];
    float own = gid == 0 ? a0 : gid == 1 ? a1 : gid == 2 ? a2 : a3;
    float vi = own, vf = own, vg = own, vo = own;   // slot gid holds own
#pragma unroll
    for (int cc = 1; cc < 4; ++cc) {
      int sg = (gid + cc) & 3;                      // which acc-e to offer
      float sv = sg == 0 ? a0 : sg == 1 ? a1 : sg == 2 ? a2 : a3;
      int src = (lane & 48) + (((gid - cc) & 3) << 2) + cl;
      float rv = __shfl(sv, src);                   // gate (gid-cc)&3 @ e=gid
      int rg = (gid - cc) & 3;
      vi = (rg == 0) ? rv : vi;
      vf = (rg == 1) ? rv : vf;
      vg = (rg == 2) ? rv : vg;
      vo = (rg == 3) ? rv : vo;
    }
    float giv = vi + basev[0];
    float gfv = vf + basev[1];
    float ggv = vg + basev[2];
    float gov = vo + basev[3];
    c = sigf(gfv) * c + sigf(giv) * tanh_(ggv);
    float h = sigf(gov) * tanh_(c);

    if (t < T_ - 1) {
      const int slot = t & 3;
      // pack 4 consecutive lanes (same row, cols cl=0..3) into one word
      union { _Float16 f; unsigned short u; } cv; cv.f = (_Float16)h;
      unsigned int hu = cv.u;
      const int lb = lane & ~3;
      unsigned int u0 = __shfl(hu, lb);
      unsigned int u1 = __shfl(hu, lb + 1);
      unsigned int u2 = __shfl(hu, lb + 2);
      unsigned int u3 = __shfl(hu, lb + 3);
      if (packer) {
        if (t >= 2)
          __hip_atomic_store(&hbuf[((long)((t - 2) & 3) << 14) + pword], 0ULL,
                             __ATOMIC_RELAXED, __HIP_MEMORY_SCOPE_AGENT);
        ull w = (ull)(u0 & 0xFFFFu)
              | ((ull)(u1 & 0xFFFFu) << 16)
              | ((ull)(u2 & 0xFFFFu) << 32)
              | ((ull)(u3 & 0xFFFFu) << 48);
        __hip_atomic_store(&hbuf[((long)slot << 14) + pword], ~w,
                           __ATOMIC_RELAXED, __HIP_MEMORY_SCOPE_AGENT);
      }

      // stream outputs while the publish propagates
      stout(dout, out2off + orow_base + (long)t * H_, h, bf);
      hs16[orow_base + (long)t * H_] = (_Float16)h;

      // poll own 4 unique words; success == data in hand (one round trip)
      const ull* sb = hbuf + ((long)slot << 14);
      ull d[4] = {0, 0, 0, 0};
      unsigned int pend = 0xFu;
      int guard = 0;
      while (pend) {
        const unsigned int snap = pend;
        ull tmp[4];
#pragma unroll
        for (int i = 0; i < 4; ++i)
          if (snap & (1u << i))
            tmp[i] = __hip_atomic_load(&sb[(long)(grow + i) * 64 + lane],
                                       __ATOMIC_RELAXED, __HIP_MEMORY_SCOPE_AGENT);
#pragma unroll
        for (int i = 0; i < 4; ++i)
          if (snap & (1u << i)) {
            if (tmp[i]) { d[i] = ~tmp[i]; pend &= ~(1u << i); }
          }
        ++guard;
        if (guard > 64) __builtin_amdgcn_s_sleep(1);   // backoff
        if (guard > 500000) break;                     // safety: wrong > hung
      }
      // drain: publish + reset committed before next step's publish
      asm volatile("s_waitcnt vmcnt(0)" ::: "memory");
      const int nxt = cur ^ 1;
#pragma unroll
      for (int i = 0; i < 4; ++i)
        *(ull*)(&h_lds[nxt][wid * 4 + i][lane * 4]) = d[i];
      __syncthreads();                             // the ONLY sync per step
      cur = nxt;
    } else {
      stout(dout, out2off + orow_base + (long)t * H_, h, bf);
      hs16[orow_base + (long)t * H_] = (_Float16)h;
    }
  }
}

// ---------------------------------------------------------------------------
// K4: projection  out1[M=131072][702] = hs16[M][256] @ Wrec16^T + b_rec
// REVERTED to the R3-verified version (R4's rewrite had a fatal M/N
// decomposition bug: each wave covered only the diagonal 16x48 block).
// Grid 8192 = 2048 M-blocks (tile 64) x 4 N-blocks (tile 192). Wave w
// handles n-tiles {3w..3w+2} across ALL 4 M-strips.
__global__ void __launch_bounds__(256) k_proj(const char* ws, const void* brec,
                                              void* dout, const int* dtf) {
  const int bf  = *dtf;
  const int tid = threadIdx.x;
  const int wid = tid >> 6, lane = tid & 63, q = lane >> 4, r = lane & 15;
  const int mb = blockIdx.x & 2047, nb = blockIdx.x >> 11;
  const long mbase = (long)mb * 64;
  const int  nbase = nb * 192;
  const _Float16* hs16 = (const _Float16*)(ws + OFF_HS16);
  const _Float16* wr16 = (const _Float16*)(ws + OFF_WREC16);

  __shared__ _Float16 a_lds[64][264];
#pragma unroll
  for (int i = 0; i < 8; ++i) {
    int u = tid + i * 256;              // 2048 units of 8 halves
    int row = u >> 5, c8 = (u & 31) * 8;
    half8 v = *(const half8*)(hs16 + (mbase + row) * H_ + c8);
    *(half8*)(&a_lds[row][c8]) = v;
  }
  __syncthreads();

  half8 bfrag[3][8];
  float bias[3];
#pragma unroll
  for (int j = 0; j < 3; ++j) {
    int ncol = nbase + (wid * 3 + j) * 16 + r;
    bias[j] = 0.0f;
    if (ncol < 704) {
      const long wrow = (long)ncol * H_;
#pragma unroll
      for (int kb = 0; kb < 8; ++kb)
        bfrag[j][kb] = *(const half8*)(wr16 + wrow + kb * 32 + q * 8);
    } else {
      half8 z = {0, 0, 0, 0, 0, 0, 0, 0};
#pragma unroll
      for (int kb = 0; kb < 8; ++kb) bfrag[j][kb] = z;
    }
    if (ncol < OUT_) bias[j] = ldin(brec, ncol, bf);
  }

  floatx4 acc[3][4];
#pragma unroll
  for (int j = 0; j < 3; ++j)
#pragma unroll
    for (int ms = 0; ms < 4; ++ms) acc[j][ms] = (floatx4){0.f, 0.f, 0.f, 0.f};

#pragma unroll
  for (int ms = 0; ms < 4; ++ms) {
#pragma unroll
    for (int kb = 0; kb < 8; ++kb) {
      half8 a = *(const half8*)(&a_lds[ms * 16 + r][kb * 32 + q * 8]);
#pragma unroll
      for (int j = 0; j < 3; ++j)
        acc[j][ms] = __builtin_amdgcn_mfma_f32_16x16x32_f16(a, bfrag[j][kb], acc[j][ms], 0, 0, 0);
    }
  }

#pragma unroll
  for (int j = 0; j < 3; ++j) {
    int ncol = nbase + (wid * 3 + j) * 16 + r;
    if (ncol >= OUT_) continue;
#pragma unroll
    for (int ms = 0; ms < 4; ++ms) {
#pragma unroll
      for (int e = 0; e < 4; ++e) {
        long mrow = mbase + ms * 16 + q * 4 + e;
        stout(dout, mrow * (long)OUT_ + ncol, acc[j][ms][e] + bias[j], bf);
      }
    }
  }
}

// ---------------------------------------------------------------------------
extern "C" void kernel_launch(void* const* d_in, const int* in_sizes, int n_in,
                              void* d_out, int out_size, void* d_ws, size_t ws_size,
                              hipStream_t stream) {
  const void* embed = d_in[0];
  const void* W_ih  = d_in[1];
  const void* W_hh  = d_in[2];
  const void* b_ih  = d_in[3];
  const void* b_hh  = d_in[4];
  const void* W_rec = d_in[5];
  const void* b_rec = d_in[6];
  char* ws = (char*)d_ws;
  const int* dtf = (const int*)(ws + OFF_DTF);

  // zero dtf + all 4 hbuf slots every launch — replay-safe (0 == "not yet")
  hipMemsetAsync(ws, 0, OFF_BASE, stream);
  k_detect<<<1, 64, 0, stream>>>((const unsigned int*)embed, (int*)(ws + OFF_DTF));
  k_prep_wc<<<1024, 256, 0, stream>>>(W_ih, W_hh, (_Float16*)(ws + OFF_WC16), dtf);
  k_prep_wrec<<<704, 256, 0, stream>>>(W_rec, (_Float16*)(ws + OFF_WREC16), dtf);
  k_prep_base<<<1024, 256, 0, stream>>>(embed, W_ih, b_ih, b_hh, (float*)(ws + OFF_BASE), dtf);
  k_lstm<<<256, 256, 0, stream>>>(ws, d_out, dtf);
  k_proj<<<8192, 256, 0, stream>>>(ws, b_rec, d_out, dtf);
}